// Round 1
// baseline (1384.069 us; speedup 1.0000x reference)
//
#include <hip/hip_runtime.h>

#define BB 8
#define HH 1024
#define WW 1024
#define HW (HH*WW)

static __device__ __forceinline__ int wrapm(int i, int n) { return (i == 0) ? n - 1 : i - 1; }
static __device__ __forceinline__ int wrapp(int i, int n) { return (i == n - 1) ? 0 : i + 1; }

#define PI_F 3.14159265358979323846f

// ---------------------------------------------------------------------------
// Diffusion step: dst = src + 0.1*laplacian(src), optional sum-of-squares
// Layout of dst (and iter>=2 src): [f*8+b][HW]
// ---------------------------------------------------------------------------
__global__ __launch_bounds__(256) void k_diff(const float* __restrict__ su,
                                              const float* __restrict__ sv,
                                              float* __restrict__ dst,
                                              int do_norm, float* __restrict__ norms)
{
    __shared__ float wsum[4];
    int z = blockIdx.z;             // f*8+b
    int f = z >> 3, b = z & 7;
    const float* s = ((f == 0) ? su : sv) + (size_t)b * HW;
    float* d = dst + (size_t)z * HW;
    int y = blockIdx.y;
    int x = blockIdx.x * 256 + threadIdx.x;
    int yr = y * WW, ym = wrapm(y, HH) * WW, yp = wrapp(y, HH) * WW;
    int xm = wrapm(x, WW), xp = wrapp(x, WW);
    float c = s[yr + x];
    float lap = s[yr + xm] + s[yr + xp] + s[ym + x] + s[yp + x] - 4.0f * c;
    float v = c + 0.1f * lap;
    d[yr + x] = v;
    if (do_norm) {
        float sq = v * v;
        #pragma unroll
        for (int o = 32; o > 0; o >>= 1) sq += __shfl_down(sq, o, 64);
        int lane = threadIdx.x & 63, wid = threadIdx.x >> 6;
        if (lane == 0) wsum[wid] = sq;
        __syncthreads();
        if (threadIdx.x == 0)
            atomicAdd(&norms[z], wsum[0] + wsum[1] + wsum[2] + wsum[3]);
    }
}

// ---------------------------------------------------------------------------
// Star velocities: u* = u + DT*(-adv_u + NU*lap_u - dp_dx) + sqrt(beta)*f_u/||f_u||
// ---------------------------------------------------------------------------
__global__ __launch_bounds__(256) void k_star(const float* __restrict__ X,
                                              const float* __restrict__ beta,
                                              const float* __restrict__ F,
                                              const float* __restrict__ norms,
                                              float* __restrict__ UV)
{
    int b = blockIdx.z;
    int y = blockIdx.y;
    int x = blockIdx.x * 256 + threadIdx.x;
    const float* u = X + (size_t)(b * 3 + 0) * HW;
    const float* v = X + (size_t)(b * 3 + 1) * HW;
    const float* p = X + (size_t)(b * 3 + 2) * HW;
    int yr = y * WW, ym = wrapm(y, HH) * WW, yp = wrapp(y, HH) * WW;
    int xm = wrapm(x, WW), xp = wrapp(x, WW);

    float uc = u[yr + x], ul = u[yr + xm], ur = u[yr + xp], uu = u[ym + x], ud = u[yp + x];
    float vc = v[yr + x], vl = v[yr + xm], vr = v[yr + xp], vu = v[ym + x], vd = v[yp + x];

    float adv_u = uc * (0.5f * (ur - ul)) + vc * (0.5f * (ud - uu));
    float adv_v = uc * (0.5f * (vr - vl)) + vc * (0.5f * (vd - vu));
    float lap_u = ul + ur + uu + ud - 4.0f * uc;
    float lap_v = vl + vr + vu + vd - 4.0f * vc;
    float dpdx = 0.5f * (p[yr + xp] - p[yr + xm]);
    float dpdy = 0.5f * (p[yp + x] - p[ym + x]);

    float sb = sqrtf(beta[b]);
    float fu = F[(size_t)(0 * BB + b) * HW + yr + x];
    float fv = F[(size_t)(1 * BB + b) * HW + yr + x];
    float inu = 1.0f / fmaxf(sqrtf(norms[b]), 1e-12f);
    float inv = 1.0f / fmaxf(sqrtf(norms[BB + b]), 1e-12f);

    float un = uc + 0.01f * (-adv_u + 0.01f * lap_u - dpdx) + sb * fu * inu;
    float vn = vc + 0.01f * (-adv_v + 0.01f * lap_v - dpdy) + sb * fv * inv;

    UV[(size_t)(0 * BB + b) * HW + yr + x] = un;
    UV[(size_t)(1 * BB + b) * HW + yr + x] = vn;
}

// ---------------------------------------------------------------------------
// Divergence of star velocities
// ---------------------------------------------------------------------------
__global__ __launch_bounds__(256) void k_divk(const float* __restrict__ UV,
                                              float* __restrict__ D)
{
    int b = blockIdx.z;
    int y = blockIdx.y;
    int x = blockIdx.x * 256 + threadIdx.x;
    int yr = y * WW, ym = wrapm(y, HH) * WW, yp = wrapp(y, HH) * WW;
    int xm = wrapm(x, WW), xp = wrapp(x, WW);
    const float* us = UV + (size_t)b * HW;
    const float* vs = UV + (size_t)(BB + b) * HW;
    D[(size_t)b * HW + yr + x] =
        0.5f * (us[yr + xp] - us[yr + xm]) + 0.5f * (vs[yp + x] - vs[ym + x]);
}

// ---------------------------------------------------------------------------
// FFT helpers (length 1024, LDS, 256 threads)
// Twiddle tables: stage with half-span len at offset (1024-2*len), len entries
// of exp(-i*pi*j/len).
// ---------------------------------------------------------------------------
static __device__ __forceinline__ void fft_tables(float* twr, float* twi)
{
    for (int len = 512; len >= 1; len >>= 1) {
        int off = 1024 - 2 * len;
        float fac = -PI_F / (float)len;
        for (int j = threadIdx.x; j < len; j += 256) {
            float sn, cs;
            sincosf(fac * (float)j, &sn, &cs);
            twr[off + j] = cs;
            twi[off + j] = sn;
        }
    }
}

// forward DIF: natural in -> bit-reversed out
static __device__ __forceinline__ void fft_dif(float* re, float* im,
                                               const float* twr, const float* twi)
{
    int t = threadIdx.x;
    for (int s = 9; s >= 0; --s) {
        int len = 1 << s;
        int off = 1024 - 2 * len;
        __syncthreads();
        #pragma unroll
        for (int k = 0; k < 2; ++k) {
            int bt = t + (k << 8);
            int j = bt & (len - 1);
            int i = ((bt >> s) << (s + 1)) | j;
            float ur = re[i], ui = im[i];
            float vr = re[i + len], vi = im[i + len];
            float wr = twr[off + j], wi = twi[off + j];
            re[i] = ur + vr; im[i] = ui + vi;
            float dr = ur - vr, di = ui - vi;
            re[i + len] = dr * wr - di * wi;
            im[i + len] = dr * wi + di * wr;
        }
    }
}

// inverse DIT: bit-reversed in -> natural out (unnormalized)
static __device__ __forceinline__ void fft_dit_inv(float* re, float* im,
                                                   const float* twr, const float* twi)
{
    int t = threadIdx.x;
    for (int s = 0; s <= 9; ++s) {
        int len = 1 << s;
        int off = 1024 - 2 * len;
        __syncthreads();
        #pragma unroll
        for (int k = 0; k < 2; ++k) {
            int bt = t + (k << 8);
            int j = bt & (len - 1);
            int i = ((bt >> s) << (s + 1)) | j;
            float ur = re[i], ui = im[i];
            float vr = re[i + len], vi = im[i + len];
            float wr = twr[off + j], wi = -twi[off + j];   // conj for inverse
            float tr = vr * wr - vi * wi;
            float ti = vr * wi + vi * wr;
            re[i] = ur + tr;       im[i] = ui + ti;
            re[i + len] = ur - tr; im[i + len] = ui - ti;
        }
    }
}

// Pass A: real rows -> complex rows (bit-reversed kx order)
__global__ __launch_bounds__(256) void k_fft_fwd_real(const float* __restrict__ src,
                                                      float2* __restrict__ dst)
{
    __shared__ float re[1024], im[1024], twr[1024], twi[1024];
    size_t base = (size_t)blockIdx.x * 1024;
    fft_tables(twr, twi);
    for (int k = threadIdx.x; k < 1024; k += 256) { re[k] = src[base + k]; im[k] = 0.0f; }
    fft_dif(re, im, twr, twi);
    __syncthreads();
    for (int k = threadIdx.x; k < 1024; k += 256) dst[base + k] = make_float2(re[k], im[k]);
}

// Pass B (on transposed data): FFT over y, Poisson scale, inverse FFT over y.
// Row index i holds kx = bitrev10(i); position g after DIF holds ky = bitrev10(g).
__global__ __launch_bounds__(256) void k_fft_poisson(float2* __restrict__ data)
{
    __shared__ float re[1024], im[1024], twr[1024], twi[1024];
    int r = blockIdx.x;
    int i = r & 1023;
    int kx = __brev((unsigned)i) >> 22;
    int fx = (kx < 512) ? kx : kx - 1024;
    float fx2 = (float)(fx * fx);
    size_t base = (size_t)r * 1024;
    fft_tables(twr, twi);
    for (int k = threadIdx.x; k < 1024; k += 256) {
        float2 v = data[base + k]; re[k] = v.x; im[k] = v.y;
    }
    fft_dif(re, im, twr, twi);
    __syncthreads();
    const float c = -1.0f / (4.0f * PI_F * PI_F * 1024.0f * 1024.0f); // incl. 1/(H*W)
    for (int k = threadIdx.x; k < 1024; k += 256) {
        int ky = __brev((unsigned)k) >> 22;
        int fy = (ky < 512) ? ky : ky - 1024;
        float k2 = fx2 + (float)(fy * fy);
        float s = (k2 > 0.0f) ? (c / k2) : 0.0f;   // DC mode zeroed
        re[k] *= s; im[k] *= s;
    }
    fft_dit_inv(re, im, twr, twi);
    __syncthreads();
    for (int k = threadIdx.x; k < 1024; k += 256) data[base + k] = make_float2(re[k], im[k]);
}

// Pass E: complex rows (bit-reversed kx order) -> inverse FFT -> real
__global__ __launch_bounds__(256) void k_fft_inv_real(const float2* __restrict__ src,
                                                      float* __restrict__ dst)
{
    __shared__ float re[1024], im[1024], twr[1024], twi[1024];
    size_t base = (size_t)blockIdx.x * 1024;
    fft_tables(twr, twi);
    for (int k = threadIdx.x; k < 1024; k += 256) {
        float2 v = src[base + k]; re[k] = v.x; im[k] = v.y;
    }
    fft_dit_inv(re, im, twr, twi);
    __syncthreads();
    for (int k = threadIdx.x; k < 1024; k += 256) dst[base + k] = re[k];
}

// ---------------------------------------------------------------------------
// Per-image complex transpose, 32x32 tiles
// ---------------------------------------------------------------------------
__global__ __launch_bounds__(256) void k_transpose(const float2* __restrict__ src,
                                                   float2* __restrict__ dst)
{
    __shared__ float2 tile[32][33];
    size_t ib = (size_t)blockIdx.z * (size_t)HW;
    int x = blockIdx.x * 32 + threadIdx.x;
    int y0 = blockIdx.y * 32 + threadIdx.y;
    #pragma unroll
    for (int k = 0; k < 4; ++k)
        tile[threadIdx.y + 8 * k][threadIdx.x] = src[ib + (size_t)(y0 + 8 * k) * WW + x];
    __syncthreads();
    int x2 = blockIdx.y * 32 + threadIdx.x;
    int y2 = blockIdx.x * 32 + threadIdx.y;
    #pragma unroll
    for (int k = 0; k < 4; ++k)
        dst[ib + (size_t)(y2 + 8 * k) * WW + x2] = tile[threadIdx.x][threadIdx.y + 8 * k];
}

// ---------------------------------------------------------------------------
// Final projection + output stack
// ---------------------------------------------------------------------------
__global__ __launch_bounds__(256) void k_final(const float* __restrict__ UV,
                                               const float* __restrict__ X,
                                               const float* __restrict__ PC,
                                               float* __restrict__ out)
{
    int b = blockIdx.z;
    int y = blockIdx.y;
    int x = blockIdx.x * 256 + threadIdx.x;
    int yr = y * WW, ym = wrapm(y, HH) * WW, yp = wrapp(y, HH) * WW;
    int xm = wrapm(x, WW), xp = wrapp(x, WW);
    const float* pc = PC + (size_t)b * HW;
    float un = UV[(size_t)(0 * BB + b) * HW + yr + x] - 0.5f * (pc[yr + xp] - pc[yr + xm]);
    float vn = UV[(size_t)(1 * BB + b) * HW + yr + x] - 0.5f * (pc[yp + x] - pc[ym + x]);
    float pn = X[(size_t)(b * 3 + 2) * HW + yr + x] + pc[yr + x];
    out[(size_t)(b * 3 + 0) * HW + yr + x] = un;
    out[(size_t)(b * 3 + 1) * HW + yr + x] = vn;
    out[(size_t)(b * 3 + 2) * HW + yr + x] = pn;
}

extern "C" void kernel_launch(void* const* d_in, const int* in_sizes, int n_in,
                              void* d_out, int out_size, void* d_ws, size_t ws_size,
                              hipStream_t stream)
{
    const float* X    = (const float*)d_in[0];
    const float* beta = (const float*)d_in[1];
    const float* fu   = (const float*)d_in[2];
    const float* fv   = (const float*)d_in[3];
    float* out = (float*)d_out;
    float* ws  = (float*)d_ws;

    const size_t NF = (size_t)2 * BB * HW;   // 16M floats
    float* F1  = ws;                         // 16M floats
    float* F2  = F1 + NF;                    // 16M floats (aliases C1)
    float* UV  = F2 + NF;                    // 16M floats
    float* D   = UV + NF;                    // 8M floats (div, later p_corr)
    float* C2f = D + (size_t)BB * HW;        // 16M floats (complex buffer)
    float* NRM = C2f + NF;                   // 16 floats
    float2* C1 = (float2*)F2;
    float2* C2 = (float2*)C2f;

    hipMemsetAsync(NRM, 0, 16 * sizeof(float), stream);

    dim3 blk(256);
    dim3 gridF(WW / 256, HH, 2 * BB);
    dim3 gridB(WW / 256, HH, BB);

    // 3 diffusion iterations of f_u/f_v; norm accumulated on the last
    k_diff<<<gridF, blk, 0, stream>>>(fu, fv, F1, 0, nullptr);
    k_diff<<<gridF, blk, 0, stream>>>(F1, F1 + (size_t)BB * HW, F2, 0, nullptr);
    k_diff<<<gridF, blk, 0, stream>>>(F2, F2 + (size_t)BB * HW, F1, 1, NRM);

    k_star<<<gridB, blk, 0, stream>>>(X, beta, F1, NRM, UV);
    k_divk<<<gridB, blk, 0, stream>>>(UV, D);

    // Poisson solve via 2D FFT
    k_fft_fwd_real<<<BB * HH, blk, 0, stream>>>(D, C1);
    dim3 tgrid(32, 32, BB), tblk(32, 8);
    k_transpose<<<tgrid, tblk, 0, stream>>>(C1, C2);
    k_fft_poisson<<<BB * HH, blk, 0, stream>>>(C2);
    k_transpose<<<tgrid, tblk, 0, stream>>>(C2, C1);
    k_fft_inv_real<<<BB * HH, blk, 0, stream>>>(C1, D);

    k_final<<<gridB, blk, 0, stream>>>(UV, X, D, out);
}

// Round 4
// 530.256 us; speedup vs baseline: 2.6102x; 2.6102x over previous
//
#include <hip/hip_runtime.h>

#define BB 8
#define HH 1024
#define WW 1024
#define HW (HH*WW)
#define PI_F 3.14159265358979323846f

static __device__ __forceinline__ int wrapm(int i, int n) { return (i == 0) ? n - 1 : i - 1; }
static __device__ __forceinline__ int wrapp(int i, int n) { return (i == n - 1) ? 0 : i + 1; }

// ---------------------------------------------------------------------------
// Twiddle table (global, computed once per launch): per-stage concatenated,
// stage with half-span len at offset (1024-2*len), len entries exp(-i*pi*j/len)
// ---------------------------------------------------------------------------
__global__ __launch_bounds__(256) void k_twid(float2* __restrict__ tw)
{
    int tid = blockIdx.x * 256 + threadIdx.x;   // grid 4x256 = 1024 threads
    for (int len = 512; len >= 1; len >>= 1) {
        int off = 1024 - 2 * len;
        float fac = -PI_F / (float)len;
        for (int j = tid; j < len; j += 1024) {
            float sn, cs;
            sincosf(fac * (float)j, &sn, &cs);
            tw[off + j] = make_float2(cs, sn);
        }
    }
}

// ---------------------------------------------------------------------------
// Fused 3x diffusion of f_u/f_v + L2 norm accumulation.
// Tile: 64x32 output, halo 3 -> 70x38 load, ping-pong in LDS.
// dst layout [f*8+b][HW]
// ---------------------------------------------------------------------------
#define TDX 64
#define TDY 32
#define LX 70
#define LY 38
#define LP 72   // padded LDS row stride

__global__ __launch_bounds__(256) void k_diff3(const float* __restrict__ su,
                                               const float* __restrict__ sv,
                                               float* __restrict__ dst,
                                               float* __restrict__ norms)
{
    __shared__ float A[LY * LP], Bf[LY * LP];
    __shared__ float wsum[4];
    int z = blockIdx.z;            // f*8+b
    int f = z >> 3, b = z & 7;
    const float* s = ((f == 0) ? su : sv) + (size_t)b * HW;
    float* d = dst + (size_t)z * HW;
    int x0 = blockIdx.x * TDX - 3;
    int y0 = blockIdx.y * TDY - 3;
    int tx = threadIdx.x & 31, ty = threadIdx.x >> 5;   // 32 x 8

    // load 70x38 tile (wrap via &1023)
    for (int r = ty; r < LY; r += 8) {
        const float* row = s + (size_t)((y0 + r) & (HH - 1)) * WW;
        for (int c = tx; c < LX; c += 32)
            A[r * LP + c] = row[(x0 + c) & (WW - 1)];
    }
    __syncthreads();

    // iter 1: A -> Bf (interior rows 1..36, cols 1..68)
    for (int r = 1 + ty; r <= 36; r += 8)
        for (int c = 1 + tx; c <= 68; c += 32) {
            float cc = A[r * LP + c];
            Bf[r * LP + c] = cc + 0.1f * (A[r * LP + c - 1] + A[r * LP + c + 1] +
                                          A[(r - 1) * LP + c] + A[(r + 1) * LP + c] - 4.0f * cc);
        }
    __syncthreads();
    // iter 2: Bf -> A
    for (int r = 1 + ty; r <= 36; r += 8)
        for (int c = 1 + tx; c <= 68; c += 32) {
            float cc = Bf[r * LP + c];
            A[r * LP + c] = cc + 0.1f * (Bf[r * LP + c - 1] + Bf[r * LP + c + 1] +
                                         Bf[(r - 1) * LP + c] + Bf[(r + 1) * LP + c] - 4.0f * cc);
        }
    __syncthreads();
    // iter 3: A -> global, accumulate sum of squares (output rows 3..34, cols 3..66)
    float sq = 0.0f;
    for (int r = 3 + ty; r <= 34; r += 8) {
        float* orow = d + (size_t)(y0 + r) * WW;
        for (int c = 3 + tx; c <= 66; c += 32) {
            float cc = A[r * LP + c];
            float v = cc + 0.1f * (A[r * LP + c - 1] + A[r * LP + c + 1] +
                                   A[(r - 1) * LP + c] + A[(r + 1) * LP + c] - 4.0f * cc);
            orow[x0 + c] = v;
            sq += v * v;
        }
    }
    #pragma unroll
    for (int o = 32; o > 0; o >>= 1) sq += __shfl_down(sq, o, 64);
    int lane = threadIdx.x & 63, wid = threadIdx.x >> 6;
    if (lane == 0) wsum[wid] = sq;
    __syncthreads();
    if (threadIdx.x == 0)
        atomicAdd(&norms[z], wsum[0] + wsum[1] + wsum[2] + wsum[3]);
}

// ---------------------------------------------------------------------------
// Star velocities
// ---------------------------------------------------------------------------
__global__ __launch_bounds__(256) void k_star(const float* __restrict__ X,
                                              const float* __restrict__ beta,
                                              const float* __restrict__ F,
                                              const float* __restrict__ norms,
                                              float* __restrict__ UV)
{
    int b = blockIdx.z;
    int y = blockIdx.y;
    int x = blockIdx.x * 256 + threadIdx.x;
    const float* u = X + (size_t)(b * 3 + 0) * HW;
    const float* v = X + (size_t)(b * 3 + 1) * HW;
    const float* p = X + (size_t)(b * 3 + 2) * HW;
    int yr = y * WW, ym = wrapm(y, HH) * WW, yp = wrapp(y, HH) * WW;
    int xm = wrapm(x, WW), xp = wrapp(x, WW);

    float uc = u[yr + x], ul = u[yr + xm], ur = u[yr + xp], uu = u[ym + x], ud = u[yp + x];
    float vc = v[yr + x], vl = v[yr + xm], vr = v[yr + xp], vu = v[ym + x], vd = v[yp + x];

    float adv_u = uc * (0.5f * (ur - ul)) + vc * (0.5f * (ud - uu));
    float adv_v = uc * (0.5f * (vr - vl)) + vc * (0.5f * (vd - vu));
    float lap_u = ul + ur + uu + ud - 4.0f * uc;
    float lap_v = vl + vr + vu + vd - 4.0f * vc;
    float dpdx = 0.5f * (p[yr + xp] - p[yr + xm]);
    float dpdy = 0.5f * (p[yp + x] - p[ym + x]);

    float sb = sqrtf(beta[b]);
    float fu = F[(size_t)(0 * BB + b) * HW + yr + x];
    float fv = F[(size_t)(1 * BB + b) * HW + yr + x];
    float inu = 1.0f / fmaxf(sqrtf(norms[b]), 1e-12f);
    float inv = 1.0f / fmaxf(sqrtf(norms[BB + b]), 1e-12f);

    float un = uc + 0.01f * (-adv_u + 0.01f * lap_u - dpdx) + sb * fu * inu;
    float vn = vc + 0.01f * (-adv_v + 0.01f * lap_v - dpdy) + sb * fv * inv;

    UV[(size_t)(0 * BB + b) * HW + yr + x] = un;
    UV[(size_t)(1 * BB + b) * HW + yr + x] = vn;
}

// ---------------------------------------------------------------------------
// Divergence, batch-pair packed: D[q] = div(b=2q) + i*div(b=2q+1)
// ---------------------------------------------------------------------------
__global__ __launch_bounds__(256) void k_div2(const float* __restrict__ UV,
                                              float2* __restrict__ D)
{
    int q = blockIdx.z;            // pair 0..3
    int y = blockIdx.y;
    int x = blockIdx.x * 256 + threadIdx.x;
    int yr = y * WW, ym = wrapm(y, HH) * WW, yp = wrapp(y, HH) * WW;
    int xm = wrapm(x, WW), xp = wrapp(x, WW);
    int b0 = 2 * q, b1 = 2 * q + 1;
    const float* u0 = UV + (size_t)b0 * HW;
    const float* v0 = UV + (size_t)(BB + b0) * HW;
    const float* u1 = UV + (size_t)b1 * HW;
    const float* v1 = UV + (size_t)(BB + b1) * HW;
    float d0 = 0.5f * (u0[yr + xp] - u0[yr + xm]) + 0.5f * (v0[yp + x] - v0[ym + x]);
    float d1 = 0.5f * (u1[yr + xp] - u1[yr + xm]) + 0.5f * (v1[yp + x] - v1[ym + x]);
    D[(size_t)q * HW + yr + x] = make_float2(d0, d1);
}

// ---------------------------------------------------------------------------
// FFT helpers (length 1024, LDS, 256 threads)
// ---------------------------------------------------------------------------
static __device__ __forceinline__ void load_tables(const float2* __restrict__ tw,
                                                   float* twr, float* twi)
{
    for (int j = threadIdx.x; j < 1024; j += 256) {
        float2 w = tw[j];
        twr[j] = w.x; twi[j] = w.y;
    }
}

// forward DIF: natural in -> bit-reversed out
static __device__ __forceinline__ void fft_dif(float* re, float* im,
                                               const float* twr, const float* twi)
{
    int t = threadIdx.x;
    for (int s = 9; s >= 0; --s) {
        int len = 1 << s;
        int off = 1024 - 2 * len;
        __syncthreads();
        #pragma unroll
        for (int k = 0; k < 2; ++k) {
            int bt = t + (k << 8);
            int j = bt & (len - 1);
            int i = ((bt >> s) << (s + 1)) | j;
            float ur = re[i], ui = im[i];
            float vr = re[i + len], vi = im[i + len];
            float wr = twr[off + j], wi = twi[off + j];
            re[i] = ur + vr; im[i] = ui + vi;
            float dr = ur - vr, di = ui - vi;
            re[i + len] = dr * wr - di * wi;
            im[i + len] = dr * wi + di * wr;
        }
    }
}

// inverse DIT: bit-reversed in -> natural out (unnormalized)
static __device__ __forceinline__ void fft_dit_inv(float* re, float* im,
                                                   const float* twr, const float* twi)
{
    int t = threadIdx.x;
    for (int s = 0; s <= 9; ++s) {
        int len = 1 << s;
        int off = 1024 - 2 * len;
        __syncthreads();
        #pragma unroll
        for (int k = 0; k < 2; ++k) {
            int bt = t + (k << 8);
            int j = bt & (len - 1);
            int i = ((bt >> s) << (s + 1)) | j;
            float ur = re[i], ui = im[i];
            float vr = re[i + len], vi = im[i + len];
            float wr = twr[off + j], wi = -twi[off + j];
            float tr = vr * wr - vi * wi;
            float ti = vr * wi + vi * wr;
            re[i] = ur + tr;       im[i] = ui + ti;
            re[i + len] = ur - tr; im[i + len] = ui - ti;
        }
    }
}

// Pass A: forward row FFT (natural -> bit-reversed)
__global__ __launch_bounds__(256) void k_fft_fwd(const float2* __restrict__ src,
                                                 float2* __restrict__ dst,
                                                 const float2* __restrict__ tw)
{
    __shared__ float re[1024], im[1024], twr[1024], twi[1024];
    size_t base = (size_t)blockIdx.x * 1024;
    load_tables(tw, twr, twi);
    for (int k = threadIdx.x; k < 1024; k += 256) {
        float2 v = src[base + k]; re[k] = v.x; im[k] = v.y;
    }
    fft_dif(re, im, twr, twi);
    __syncthreads();
    for (int k = threadIdx.x; k < 1024; k += 256) dst[base + k] = make_float2(re[k], im[k]);
}

// Pass B (transposed): col FFT, Poisson scale, inverse col FFT. In place.
__global__ __launch_bounds__(256) void k_fft_poisson(float2* __restrict__ data,
                                                     const float2* __restrict__ tw)
{
    __shared__ float re[1024], im[1024], twr[1024], twi[1024];
    int r = blockIdx.x;
    int i = r & 1023;
    int kx = __brev((unsigned)i) >> 22;
    int fx = (kx < 512) ? kx : kx - 1024;
    float fx2 = (float)(fx * fx);
    size_t base = (size_t)r * 1024;
    load_tables(tw, twr, twi);
    for (int k = threadIdx.x; k < 1024; k += 256) {
        float2 v = data[base + k]; re[k] = v.x; im[k] = v.y;
    }
    fft_dif(re, im, twr, twi);
    __syncthreads();
    const float c = -1.0f / (4.0f * PI_F * PI_F * 1024.0f * 1024.0f); // incl. 1/(H*W)
    for (int k = threadIdx.x; k < 1024; k += 256) {
        int ky = __brev((unsigned)k) >> 22;
        int fy = (ky < 512) ? ky : ky - 1024;
        float k2 = fx2 + (float)(fy * fy);
        float s = (k2 > 0.0f) ? (c / k2) : 0.0f;   // DC zeroed
        re[k] *= s; im[k] *= s;
    }
    fft_dit_inv(re, im, twr, twi);
    __syncthreads();
    for (int k = threadIdx.x; k < 1024; k += 256) data[base + k] = make_float2(re[k], im[k]);
}

// Pass C: inverse row FFT (bit-reversed -> natural)
__global__ __launch_bounds__(256) void k_fft_inv(const float2* __restrict__ src,
                                                 float2* __restrict__ dst,
                                                 const float2* __restrict__ tw)
{
    __shared__ float re[1024], im[1024], twr[1024], twi[1024];
    size_t base = (size_t)blockIdx.x * 1024;
    load_tables(tw, twr, twi);
    for (int k = threadIdx.x; k < 1024; k += 256) {
        float2 v = src[base + k]; re[k] = v.x; im[k] = v.y;
    }
    fft_dit_inv(re, im, twr, twi);
    __syncthreads();
    for (int k = threadIdx.x; k < 1024; k += 256) dst[base + k] = make_float2(re[k], im[k]);
}

// ---------------------------------------------------------------------------
// Per-image complex transpose, 32x32 tiles (4 packed images)
// ---------------------------------------------------------------------------
__global__ __launch_bounds__(256) void k_transpose(const float2* __restrict__ src,
                                                   float2* __restrict__ dst)
{
    __shared__ float2 tile[32][33];
    size_t ib = (size_t)blockIdx.z * (size_t)HW;
    int x = blockIdx.x * 32 + threadIdx.x;
    int y0 = blockIdx.y * 32 + threadIdx.y;
    #pragma unroll
    for (int k = 0; k < 4; ++k)
        tile[threadIdx.y + 8 * k][threadIdx.x] = src[ib + (size_t)(y0 + 8 * k) * WW + x];
    __syncthreads();
    int x2 = blockIdx.y * 32 + threadIdx.x;
    int y2 = blockIdx.x * 32 + threadIdx.y;
    #pragma unroll
    for (int k = 0; k < 4; ++k)
        dst[ib + (size_t)(y2 + 8 * k) * WW + x2] = tile[threadIdx.x][threadIdx.y + 8 * k];
}

// ---------------------------------------------------------------------------
// Final projection + output stack (PC packed per batch-pair)
// ---------------------------------------------------------------------------
__global__ __launch_bounds__(256) void k_final(const float* __restrict__ UV,
                                               const float* __restrict__ X,
                                               const float2* __restrict__ PC,
                                               float* __restrict__ out)
{
    int b = blockIdx.z;
    int q = b >> 1, comp = b & 1;
    int y = blockIdx.y;
    int x = blockIdx.x * 256 + threadIdx.x;
    int yr = y * WW, ym = wrapm(y, HH) * WW, yp = wrapp(y, HH) * WW;
    int xm = wrapm(x, WW), xp = wrapp(x, WW);
    const float2* pc = PC + (size_t)q * HW;
    float2 pxp = pc[yr + xp], pxm = pc[yr + xm];
    float2 pyp = pc[yp + x],  pym = pc[ym + x];
    float2 pcc = pc[yr + x];
    float gx, gy, pv;
    if (comp == 0) { gx = 0.5f * (pxp.x - pxm.x); gy = 0.5f * (pyp.x - pym.x); pv = pcc.x; }
    else           { gx = 0.5f * (pxp.y - pxm.y); gy = 0.5f * (pyp.y - pym.y); pv = pcc.y; }
    float un = UV[(size_t)(0 * BB + b) * HW + yr + x] - gx;
    float vn = UV[(size_t)(1 * BB + b) * HW + yr + x] - gy;
    float pn = X[(size_t)(b * 3 + 2) * HW + yr + x] + pv;
    out[(size_t)(b * 3 + 0) * HW + yr + x] = un;
    out[(size_t)(b * 3 + 1) * HW + yr + x] = vn;
    out[(size_t)(b * 3 + 2) * HW + yr + x] = pn;
}

extern "C" void kernel_launch(void* const* d_in, const int* in_sizes, int n_in,
                              void* d_out, int out_size, void* d_ws, size_t ws_size,
                              hipStream_t stream)
{
    const float* X    = (const float*)d_in[0];
    const float* beta = (const float*)d_in[1];
    const float* fu   = (const float*)d_in[2];
    const float* fv   = (const float*)d_in[3];
    float* out = (float*)d_out;
    float* ws  = (float*)d_ws;

    float* F1  = ws;                              // 16M floats (64MB)
    float* UV  = F1 + (size_t)2 * BB * HW;        // 16M floats (64MB)
    float* Dpf = UV + (size_t)2 * BB * HW;        // 8M floats  (32MB, 4 complex imgs)
    float* Cbf = Dpf + (size_t)BB * HW;           // 8M floats  (32MB)
    float* TWf = Cbf + (size_t)BB * HW;           // 2048 floats
    float* NRM = TWf + 2048;                      // 16 floats
    float2* Dp = (float2*)Dpf;
    float2* Cb = (float2*)Cbf;
    float2* TW = (float2*)TWf;

    (void)hipMemsetAsync(NRM, 0, 16 * sizeof(float), stream);
    k_twid<<<4, 256, 0, stream>>>(TW);

    dim3 blk(256);
    dim3 gridD(WW / TDX, HH / TDY, 2 * BB);       // 16 x 32 x 16
    dim3 gridB(WW / 256, HH, BB);
    dim3 gridQ(WW / 256, HH, BB / 2);
    dim3 tgrid(32, 32, BB / 2), tblk(32, 8);

    k_diff3<<<gridD, blk, 0, stream>>>(fu, fv, F1, NRM);
    k_star<<<gridB, blk, 0, stream>>>(X, beta, F1, NRM, UV);
    k_div2<<<gridQ, blk, 0, stream>>>(UV, Dp);

    k_fft_fwd<<<(BB / 2) * HH, blk, 0, stream>>>(Dp, Cb, TW);
    k_transpose<<<tgrid, tblk, 0, stream>>>(Cb, Dp);
    k_fft_poisson<<<(BB / 2) * HH, blk, 0, stream>>>(Dp, TW);
    k_transpose<<<tgrid, tblk, 0, stream>>>(Dp, Cb);
    k_fft_inv<<<(BB / 2) * HH, blk, 0, stream>>>(Cb, Dp, TW);

    k_final<<<gridB, blk, 0, stream>>>(UV, X, Dp, out);
}